// Round 1
// baseline (170.719 us; speedup 1.0000x reference)
//
#include <hip/hip_runtime.h>

typedef __attribute__((ext_vector_type(8))) __bf16 bf16x8;
typedef __attribute__((ext_vector_type(4))) float f32x4;

#define LOG2E 1.44269504088896f

// 28 instances of dilated causal attention, each L=2048, d=64.
// Layout of q/k/v: (1, 8192, 12, 64) fp32 -> elem = tok*768 + head*64 + d.
// Block = 256 threads (4 waves); each block: one (instance, 64-row q-tile).
// Wave handles 16 q rows. KV tiles of 64 staged in swizzled LDS as bf16.

__global__ __launch_bounds__(256)
void dilattn_kernel(const float* __restrict__ Qg, const float* __restrict__ Kg,
                    const float* __restrict__ Vg, float* __restrict__ Og,
                    const int* __restrict__ causal_p)
{
    const int bid  = blockIdx.x;
    const int qt   = 31 - (bid & 31);      // heavy (diagonal-far) tiles first
    const int inst = bid >> 5;
    int head, sstart, r, off;
    if (inst < 16)      { head = inst & 3;          sstart = (inst >> 2) * 2048; r = 1; off = 0; }
    else if (inst < 24) { int j = inst - 16; head = 4 + (j & 3); sstart = (j >> 2) * 4096; r = 2; off = 1; }
    else                { head = 8 + (inst - 24);   sstart = 0;                  r = 4; off = 2; }

    const int causal = *causal_p;
    const int tid  = threadIdx.x;
    const int lane = tid & 63;
    const int wave = tid >> 6;
    const int l15  = lane & 15;
    const int lhi  = lane >> 4;            // 0..3

    __shared__ __bf16 K_lds[64 * 64];      // [krow][d], swizzled
    __shared__ __bf16 Vt_lds[64 * 64];     // [d][krow], swizzled (V transposed)
    __shared__ __bf16 P_lds[4][16 * 64];   // per-wave P bridge, swizzled

    // ---- Q fragments in registers (softmax scale * log2e folded into Q) ----
    const int qrow_base = qt * 64 + wave * 16;
    const float qscale = 0.125f * LOG2E;
    bf16x8 qfrag[2];
    {
        int qr = qrow_base + l15;
        long qtok = sstart + off + (long)r * qr;
        const float* qp = Qg + qtok * 768 + head * 64 + lhi * 8;
#pragma unroll
        for (int dc = 0; dc < 2; dc++) {
            f32x4 a = *(const f32x4*)(qp + dc * 32);
            f32x4 b = *(const f32x4*)(qp + dc * 32 + 4);
#pragma unroll
            for (int j = 0; j < 4; j++) {
                qfrag[dc][j]     = (__bf16)(a[j] * qscale);
                qfrag[dc][4 + j] = (__bf16)(b[j] * qscale);
            }
        }
    }

    f32x4 acc[4] = {};                                        // O accum: row=(lhi*4+reg), col=dt*16+l15
    float m_run[4] = {-INFINITY, -INFINITY, -INFINITY, -INFINITY};
    float l_run[4] = {0.f, 0.f, 0.f, 0.f};

    const int nkt = causal ? (qt + 1) : 32;
    const int kk = tid >> 2;               // 0..63 : kv row staged by this thread
    const int quarter = tid & 3;           // 0..3  : 16-wide d chunk

    for (int kt = 0; kt < nkt; kt++) {
        __syncthreads();                   // prior tile's LDS reads done
        // ---- stage K (row-major) and V (transposed) as bf16, swizzled ----
        {
            long ktok = sstart + off + (long)r * (kt * 64 + kk);
            const float* kp = Kg + ktok * 768 + head * 64 + quarter * 16;
            const float* vp = Vg + ktok * 768 + head * 64 + quarter * 16;
            f32x4 k0 = *(const f32x4*)(kp);
            f32x4 k1 = *(const f32x4*)(kp + 4);
            f32x4 k2 = *(const f32x4*)(kp + 8);
            f32x4 k3 = *(const f32x4*)(kp + 12);
            f32x4 v0 = *(const f32x4*)(vp);
            f32x4 v1 = *(const f32x4*)(vp + 4);
            f32x4 v2 = *(const f32x4*)(vp + 8);
            f32x4 v3 = *(const f32x4*)(vp + 12);
            bf16x8 w0, w1;
#pragma unroll
            for (int j = 0; j < 4; j++) {
                w0[j] = (__bf16)k0[j]; w0[4 + j] = (__bf16)k1[j];
                w1[j] = (__bf16)k2[j]; w1[4 + j] = (__bf16)k3[j];
            }
            int kbase = kk * 128 + quarter * 32;
            int ksw = (kk & 7) << 4;
            *(bf16x8*)((char*)K_lds + ((kbase)      ^ ksw)) = w0;
            *(bf16x8*)((char*)K_lds + ((kbase + 16) ^ ksw)) = w1;
#pragma unroll
            for (int j = 0; j < 4; j++) {
                int d0 = quarter * 16 + j;
                *(__bf16*)((char*)Vt_lds + ((d0 * 128 + kk * 2) ^ ((d0 & 7) << 4))) = (__bf16)v0[j];
                int d1 = d0 + 4;
                *(__bf16*)((char*)Vt_lds + ((d1 * 128 + kk * 2) ^ ((d1 & 7) << 4))) = (__bf16)v1[j];
                int d2 = d0 + 8;
                *(__bf16*)((char*)Vt_lds + ((d2 * 128 + kk * 2) ^ ((d2 & 7) << 4))) = (__bf16)v2[j];
                int d3 = d0 + 12;
                *(__bf16*)((char*)Vt_lds + ((d3 * 128 + kk * 2) ^ ((d3 & 7) << 4))) = (__bf16)v3[j];
            }
        }
        __syncthreads();                   // tile staged

        // ---- S = (Q*scale*log2e) K^T  (log2 domain) ----
        f32x4 s[4];
#pragma unroll
        for (int nt = 0; nt < 4; nt++) {
            f32x4 c = {};
#pragma unroll
            for (int dc = 0; dc < 2; dc++) {
                int krow = nt * 16 + l15;
                const bf16x8 kf = *(const bf16x8*)((char*)K_lds +
                    ((krow * 128 + dc * 64 + lhi * 16) ^ ((krow & 7) << 4)));
                c = __builtin_amdgcn_mfma_f32_16x16x32_bf16(qfrag[dc], kf, c, 0, 0, 0);
            }
            s[nt] = c;
        }

        // ---- causal mask (only the diagonal tile needs it) ----
        if (causal && kt == qt) {
#pragma unroll
            for (int nt = 0; nt < 4; nt++) {
                int kc = kt * 64 + nt * 16 + l15;
#pragma unroll
                for (int reg = 0; reg < 4; reg++) {
                    int qr = qrow_base + lhi * 4 + reg;
                    if (kc > qr) s[nt][reg] = -INFINITY;
                }
            }
        }

        // ---- online softmax (wave-parallel: 16-lane row groups) ----
        float sc_reg[4];
#pragma unroll
        for (int reg = 0; reg < 4; reg++) {
            float mt = fmaxf(fmaxf(s[0][reg], s[1][reg]), fmaxf(s[2][reg], s[3][reg]));
#pragma unroll
            for (int x = 1; x < 16; x <<= 1) mt = fmaxf(mt, __shfl_xor(mt, x));
            float mn = fmaxf(m_run[reg], mt);
            float sc = exp2f(m_run[reg] - mn);
            float ps = 0.f;
#pragma unroll
            for (int nt = 0; nt < 4; nt++) {
                float p = exp2f(s[nt][reg] - mn);
                s[nt][reg] = p;
                ps += p;
            }
#pragma unroll
            for (int x = 1; x < 16; x <<= 1) ps += __shfl_xor(ps, x);
            l_run[reg] = l_run[reg] * sc + ps;
            m_run[reg] = mn;
            sc_reg[reg] = sc;
        }
#pragma unroll
        for (int dt = 0; dt < 4; dt++)
#pragma unroll
            for (int reg = 0; reg < 4; reg++) acc[dt][reg] *= sc_reg[reg];

        // ---- P (C-layout) -> wave-private swizzled LDS, bf16 ----
        char* pl = (char*)P_lds[wave];
#pragma unroll
        for (int reg = 0; reg < 4; reg++) {
            int row = lhi * 4 + reg;
            int rs = (row & 7) << 4;
#pragma unroll
            for (int nt = 0; nt < 4; nt++) {
                int colb = (nt * 16 + l15) * 2;
                *(__bf16*)(pl + ((row * 128 + colb) ^ rs)) = (__bf16)s[nt][reg];
            }
        }

        // ---- O += P V ----
#pragma unroll
        for (int kc = 0; kc < 2; kc++) {
            const bf16x8 pf = *(const bf16x8*)(pl +
                ((l15 * 128 + kc * 64 + lhi * 16) ^ ((l15 & 7) << 4)));
#pragma unroll
            for (int dt = 0; dt < 4; dt++) {
                int drow = dt * 16 + l15;
                const bf16x8 vf = *(const bf16x8*)((char*)Vt_lds +
                    ((drow * 128 + kc * 64 + lhi * 16) ^ ((drow & 7) << 4)));
                acc[dt] = __builtin_amdgcn_mfma_f32_16x16x32_bf16(pf, vf, acc[dt], 0, 0, 0);
            }
        }
    }

    // ---- epilogue: O / l, scatter to dilated token positions ----
#pragma unroll
    for (int reg = 0; reg < 4; reg++) {
        float inv = 1.0f / l_run[reg];
        int qr = qrow_base + lhi * 4 + reg;
        long tok = sstart + off + (long)r * qr;
        float* op = Og + tok * 768 + head * 64 + l15;
#pragma unroll
        for (int dt = 0; dt < 4; dt++) op[dt * 16] = acc[dt][reg] * inv;
    }
}

extern "C" void kernel_launch(void* const* d_in, const int* in_sizes, int n_in,
                              void* d_out, int out_size, void* d_ws, size_t ws_size,
                              hipStream_t stream)
{
    const float* q = (const float*)d_in[0];
    const float* k = (const float*)d_in[1];
    const float* v = (const float*)d_in[2];
    const int* causal = (const int*)d_in[3];
    float* out = (float*)d_out;

    // zero output (non-dilated positions must be exactly 0)
    hipMemsetAsync(d_out, 0, (size_t)out_size * sizeof(float), stream);

    dilattn_kernel<<<dim3(28 * 32), dim3(256), 0, stream>>>(q, k, v, out, causal);
}